// Round 12
// baseline (443.492 us; speedup 1.0000x reference)
//
#include <hip/hip_runtime.h>
#include <hip/hip_bf16.h>

// GraphNet: N=50000 nodes, F=128 feats, H=128, MH=256, E=800000 edges
// Inputs FP32; bf16 workspace copies for MFMA; fp32 MFMA accumulation.
// Edge MLP decomposed: P[n]=h2[n]@W1s^T, Q[n]=h2[n]@W1d^T+bm1 (node GEMM, PERMUTED col
// layout col'=c*16+nt for vectorized stores), then out[e]=relu(P[src]+Q[dst]).Wm2p + bm2.
#define NN 50000
#define F 128
#define EE 800000
#define MHD 256

typedef __attribute__((ext_vector_type(8))) short bf16x8;
typedef __attribute__((ext_vector_type(4))) float f32x4;

__device__ __forceinline__ float b2f(unsigned short u) {
    union { unsigned int i; float f; } v; v.i = ((unsigned)u) << 16; return v.f;
}
__device__ __forceinline__ unsigned short f2b(float f) {
    unsigned int x = __float_as_uint(f);
    unsigned int r = x + 0x7fffu + ((x >> 16) & 1u);   // RNE
    return (unsigned short)(r >> 16);
}

// ---------------- fp32 -> bf16 cast of x ----------------
__global__ __launch_bounds__(256) void cast_x_kernel(
    const float* __restrict__ in, unsigned short* __restrict__ out) {
    int i = (blockIdx.x * 256 + threadIdx.x) * 4;
    float4 v = *(const float4*)(in + i);
    ushort4 o; o.x = f2b(v.x); o.y = f2b(v.y); o.z = f2b(v.z); o.w = f2b(v.w);
    *(ushort4*)(out + i) = o;
}

// ---------------- fp32 -> bf16 cast of the 5 weight matrices ----------------
__global__ __launch_bounds__(256) void cast_w_kernel(
    const float* __restrict__ W1l, const float* __restrict__ W1r,
    const float* __restrict__ W2l, const float* __restrict__ W2r,
    const float* __restrict__ Wm1, unsigned short* __restrict__ wb) {
    int i = (blockIdx.x * 256 + threadIdx.x) * 4;        // 131072 elems / 4
    const float* p;
    if (i < 16384)      p = W1l + i;
    else if (i < 32768) p = W1r + (i - 16384);
    else if (i < 49152) p = W2l + (i - 32768);
    else if (i < 65536) p = W2r + (i - 49152);
    else                p = Wm1 + (i - 65536);
    float4 v = *(const float4*)p;
    ushort4 o; o.x = f2b(v.x); o.y = f2b(v.y); o.z = f2b(v.z); o.w = f2b(v.w);
    *(ushort4*)(wb + i) = o;
}

// ---------------- edge_index canonicalize -> int32 src/dst + degree histogram ----------------
__global__ __launch_bounds__(256) void edge_cvt_hist_kernel(
    const int* __restrict__ ei, int* __restrict__ s32, int* __restrict__ d32,
    int* __restrict__ deg) {
    __shared__ int isI64;
    if (threadIdx.x == 0) {
        int z = 0;
        for (int i = 1; i < 128; i += 2) z |= ei[i];
        isI64 = (z == 0) ? 1 : 0;
    }
    __syncthreads();
    int e = blockIdx.x * 256 + threadIdx.x;
    if (e >= EE) return;
    int s, d;
    if (isI64) {
        const long long* e64 = (const long long*)ei;
        s = (int)e64[e];
        d = (int)e64[EE + e];
    } else {
        s = ei[e];
        d = ei[EE + e];
    }
    s32[e] = s;
    d32[e] = d;
    atomicAdd(&deg[d], 1);
}

// ---------------- device-wide exclusive scan of deg (3 phases) ----------------
__global__ __launch_bounds__(1024) void scan_p1_kernel(
    const int* __restrict__ deg, int* __restrict__ exloc, int* __restrict__ bsum) {
    __shared__ int part[1024];
    int t = threadIdx.x, gid = blockIdx.x * 1024 + t;
    int v = (gid < NN) ? deg[gid] : 0;
    part[t] = v;
    __syncthreads();
    for (int off = 1; off < 1024; off <<= 1) {
        int u = (t >= off) ? part[t - off] : 0;
        __syncthreads();
        part[t] += u;
        __syncthreads();
    }
    exloc[gid] = part[t] - v;
    if (t == 1023) bsum[blockIdx.x] = part[t];
}

__global__ __launch_bounds__(64) void scan_p2_kernel(int* __restrict__ bsum) {
    int t = threadIdx.x;
    int v = (t < 50) ? bsum[t] : 0;
    int orig = v;
    for (int off = 1; off < 64; off <<= 1) {
        int u = __shfl_up(v, off);
        if (t >= off) v += u;
    }
    if (t < 50) bsum[t] = v - orig;
}

__global__ __launch_bounds__(1024) void scan_p3_kernel(
    const int* __restrict__ exloc, const int* __restrict__ bsum,
    int* __restrict__ rowstart, int* __restrict__ cursor) {
    int t = threadIdx.x, gid = blockIdx.x * 1024 + t;
    if (gid > NN) return;
    if (gid == NN) { rowstart[NN] = EE; return; }
    int r = exloc[gid] + bsum[blockIdx.x];
    rowstart[gid] = r;
    cursor[gid] = r;
}

__global__ __launch_bounds__(256) void fill_kernel(
    const int* __restrict__ s32, const int* __restrict__ d32,
    int* __restrict__ cursor, int* __restrict__ nbr, int* __restrict__ eid) {
    int e = blockIdx.x * 256 + threadIdx.x;
    if (e < EE) {
        int p = atomicAdd(&cursor[d32[e]], 1);
        nbr[p] = s32[e];
        eid[p] = e;
    }
}

// ---------------- gather aggregation + mean ----------------
__global__ __launch_bounds__(256) void agg_gather_kernel(
    const unsigned short* __restrict__ xin,
    const int* __restrict__ nbr, const int* __restrict__ rowstart,
    unsigned short* __restrict__ aggb) {
    int wave = threadIdx.x >> 6, lane = threadIdx.x & 63;
    int node = blockIdx.x * 4 + wave;
    if (node >= NN) return;
    int part = lane >> 4;
    int col8 = (lane & 15) * 8;
    int beg = rowstart[node], end = rowstart[node + 1];
    float a[8] = {0,0,0,0,0,0,0,0};
    float b[8] = {0,0,0,0,0,0,0,0};
    int j = beg + part;
    for (; j + 12 < end; j += 16) {
        int s0 = nbr[j], s1 = nbr[j + 4], s2 = nbr[j + 8], s3 = nbr[j + 12];
        bf16x8 v0 = *(const bf16x8*)(xin + (size_t)s0 * F + col8);
        bf16x8 v1 = *(const bf16x8*)(xin + (size_t)s1 * F + col8);
        bf16x8 v2 = *(const bf16x8*)(xin + (size_t)s2 * F + col8);
        bf16x8 v3 = *(const bf16x8*)(xin + (size_t)s3 * F + col8);
        for (int i = 0; i < 8; i++) a[i] += b2f((unsigned short)v0[i]);
        for (int i = 0; i < 8; i++) b[i] += b2f((unsigned short)v1[i]);
        for (int i = 0; i < 8; i++) a[i] += b2f((unsigned short)v2[i]);
        for (int i = 0; i < 8; i++) b[i] += b2f((unsigned short)v3[i]);
    }
    for (; j < end; j += 4) {
        int s0 = nbr[j];
        bf16x8 v0 = *(const bf16x8*)(xin + (size_t)s0 * F + col8);
        for (int i = 0; i < 8; i++) a[i] += b2f((unsigned short)v0[i]);
    }
    float inv = 1.0f / fmaxf((float)(end - beg), 1.0f);
    unsigned short o[8];
    for (int i = 0; i < 8; i++) {
        float v = a[i] + b[i];
        v += __shfl_xor(v, 16);
        v += __shfl_xor(v, 32);
        o[i] = f2b(v * inv);
    }
    if (part == 0)
        *(bf16x8*)(aggb + (size_t)node * F + col8) = *(bf16x8*)o;
}

// ---------------- fused SAGE combine: out = relu(A1@W1^T + bias + A2@W2^T) ----------------
__global__ __launch_bounds__(256) void node_gemm_kernel(
    const unsigned short* __restrict__ A1, const unsigned short* __restrict__ A2,
    const unsigned short* __restrict__ W1, const unsigned short* __restrict__ W2,
    const float* __restrict__ bias,
    unsigned short* __restrict__ out) {
    int wave = threadIdx.x >> 6, lane = threadIdx.x & 63;
    int c = lane & 15, q = lane >> 4;
    int m0 = (blockIdx.x * 4 + wave) * 16;
    if (m0 >= NN) return;
    f32x4 acc[8];
    for (int nt = 0; nt < 8; nt++) {
        float b = bias[nt * 16 + c];
        acc[nt] = (f32x4){b, b, b, b};
    }
    int mrow = m0 + c; if (mrow > NN - 1) mrow = NN - 1;
    for (int op = 0; op < 2; op++) {
        const unsigned short* ap = (op ? A2 : A1) + (size_t)mrow * F + q * 8;
        const unsigned short* W  = op ? W2 : W1;
        for (int kb = 0; kb < 4; kb++) {
            bf16x8 a = *(const bf16x8*)(ap + kb * 32);
            for (int nt = 0; nt < 8; nt++) {
                bf16x8 b = *(const bf16x8*)(W + (size_t)(nt * 16 + c) * F + kb * 32 + q * 8);
                acc[nt] = __builtin_amdgcn_mfma_f32_16x16x32_bf16(a, b, acc[nt], 0, 0, 0);
            }
        }
    }
    for (int nt = 0; nt < 8; nt++) {
        for (int r = 0; r < 4; r++) {
            int node = m0 + q * 4 + r;
            if (node < NN) {
                float v = fmaxf(acc[nt][r], 0.0f);
                out[(size_t)node * F + nt * 16 + c] = f2b(v);
            }
        }
    }
}

// ---------------- PQ GEMM (wave-split N, permuted cols): PQ[n] bf16 [N,512] ----------------
__global__ __launch_bounds__(256) void pq_gemm_kernel(
    const unsigned short* __restrict__ h,
    const unsigned short* __restrict__ wmb,
    const float* __restrict__ bm1,
    unsigned short* __restrict__ PQ) {
    int wave = threadIdx.x >> 6, lane = threadIdx.x & 63;
    int c = lane & 15, q = lane >> 4;
    int half = wave >> 1, ntBase = (wave & 1) * 8;
    int m0 = blockIdx.x * 16;
    int mrow = m0 + c; if (mrow > NN - 1) mrow = NN - 1;
    bf16x8 a[4];
#pragma unroll
    for (int kb = 0; kb < 4; kb++)
        a[kb] = *(const bf16x8*)(h + (size_t)mrow * F + kb * 32 + q * 8);
    f32x4 acc[8];
#pragma unroll
    for (int nt = 0; nt < 8; nt++) {
        float b = half ? bm1[(ntBase + nt) * 16 + c] : 0.0f;
        acc[nt] = (f32x4){b, b, b, b};
    }
#pragma unroll
    for (int kb = 0; kb < 4; kb++) {
#pragma unroll
        for (int nt = 0; nt < 8; nt++) {
            bf16x8 b = *(const bf16x8*)(wmb + (size_t)((ntBase + nt) * 16 + c) * 256 + half * 128 + kb * 32 + q * 8);
            acc[nt] = __builtin_amdgcn_mfma_f32_16x16x32_bf16(a[kb], b, acc[nt], 0, 0, 0);
        }
    }
#pragma unroll
    for (int r = 0; r < 4; r++) {
        int node = m0 + q * 4 + r;
        if (node < NN) {
            unsigned short o[8];
#pragma unroll
            for (int nt = 0; nt < 8; nt++) o[nt] = f2b(acc[nt][r]);
            *(bf16x8*)(PQ + (size_t)node * 512 + half * 256 + c * 16 + ntBase) = *(bf16x8*)o;
        }
    }
}

// ---------------- edge dot: out[eid] = relu(P[src]+Q[dst]).Wm2p + bm2 ----------------
// One wave per dst node; 16 lanes/edge, j-loop UNROLLED x2 -> 8 edges (8x32B gathers) in
// flight per wave. bf16 unpack via dword trick: lo=v<<16, hi=v&0xffff0000 (1 bit-op/elem).
__global__ __launch_bounds__(256) void edge_dot_kernel(
    const unsigned short* __restrict__ PQ,
    const int* __restrict__ nbr, const int* __restrict__ eid,
    const int* __restrict__ rowstart,
    const float* __restrict__ Wm2, const float* __restrict__ bm2,
    float* __restrict__ out) {
    int wave = threadIdx.x >> 6, lane = threadIdx.x & 63;
    int node = blockIdx.x * 4 + wave;
    if (node >= NN) return;
    int g = lane >> 4, l16 = lane & 15;
    int col = l16 * 16;                      // 16 permuted cols per lane
    float w2f[16], qf[16];
#pragma unroll
    for (int i = 0; i < 16; i++) w2f[i] = Wm2[i * 16 + l16];   // inverse perm gather
    {
        bf16x8 q0 = *(const bf16x8*)(PQ + (size_t)node * 512 + 256 + col);
        bf16x8 q1 = *(const bf16x8*)(PQ + (size_t)node * 512 + 256 + col + 8);
#pragma unroll
        for (int i = 0; i < 8; i++) { qf[i] = b2f((unsigned short)q0[i]); qf[8 + i] = b2f((unsigned short)q1[i]); }
    }
    float b2 = bm2[0];
    int beg = rowstart[node], end = rowstart[node + 1];
    int j = beg + g;
    for (; j + 4 < end; j += 8) {            // 2 edges per group in flight
        int s0 = nbr[j], s1 = nbr[j + 4];
        int id0 = eid[j], id1 = eid[j + 4];
        uint4 a0 = *(const uint4*)(PQ + (size_t)s0 * 512 + col);
        uint4 a1 = *(const uint4*)(PQ + (size_t)s0 * 512 + col + 8);
        uint4 c0 = *(const uint4*)(PQ + (size_t)s1 * 512 + col);
        uint4 c1 = *(const uint4*)(PQ + (size_t)s1 * 512 + col + 8);
        float t0 = 0.f, t1 = 0.f;
        unsigned int w0[8] = {a0.x, a0.y, a0.z, a0.w, a1.x, a1.y, a1.z, a1.w};
        unsigned int w1[8] = {c0.x, c0.y, c0.z, c0.w, c1.x, c1.y, c1.z, c1.w};
#pragma unroll
        for (int i = 0; i < 8; i++) {
            float lo0 = __uint_as_float(w0[i] << 16);
            float hi0 = __uint_as_float(w0[i] & 0xffff0000u);
            float lo1 = __uint_as_float(w1[i] << 16);
            float hi1 = __uint_as_float(w1[i] & 0xffff0000u);
            t0 += fmaxf(lo0 + qf[2 * i], 0.f) * w2f[2 * i]
                + fmaxf(hi0 + qf[2 * i + 1], 0.f) * w2f[2 * i + 1];
            t1 += fmaxf(lo1 + qf[2 * i], 0.f) * w2f[2 * i]
                + fmaxf(hi1 + qf[2 * i + 1], 0.f) * w2f[2 * i + 1];
        }
        t0 += __shfl_xor(t0, 1);  t1 += __shfl_xor(t1, 1);
        t0 += __shfl_xor(t0, 2);  t1 += __shfl_xor(t1, 2);
        t0 += __shfl_xor(t0, 4);  t1 += __shfl_xor(t1, 4);
        t0 += __shfl_xor(t0, 8);  t1 += __shfl_xor(t1, 8);
        if (l16 == 0) { out[id0] = t0 + b2; out[id1] = t1 + b2; }
    }
    for (; j < end; j += 4) {
        int s = nbr[j];
        int id = eid[j];
        uint4 a0 = *(const uint4*)(PQ + (size_t)s * 512 + col);
        uint4 a1 = *(const uint4*)(PQ + (size_t)s * 512 + col + 8);
        unsigned int w0[8] = {a0.x, a0.y, a0.z, a0.w, a1.x, a1.y, a1.z, a1.w};
        float t = 0.f;
#pragma unroll
        for (int i = 0; i < 8; i++) {
            float lo = __uint_as_float(w0[i] << 16);
            float hi = __uint_as_float(w0[i] & 0xffff0000u);
            t += fmaxf(lo + qf[2 * i], 0.f) * w2f[2 * i]
               + fmaxf(hi + qf[2 * i + 1], 0.f) * w2f[2 * i + 1];
        }
        t += __shfl_xor(t, 1);
        t += __shfl_xor(t, 2);
        t += __shfl_xor(t, 4);
        t += __shfl_xor(t, 8);
        if (l16 == 0) out[id] = t + b2;
    }
}

extern "C" void kernel_launch(void* const* d_in, const int* in_sizes, int n_in,
                              void* d_out, int out_size, void* d_ws, size_t ws_size,
                              hipStream_t stream) {
    const float* x   = (const float*)d_in[0];
    const int*   ei  = (const int*)d_in[1];
    const float* W1l = (const float*)d_in[2];
    const float* b1l = (const float*)d_in[3];
    const float* W1r = (const float*)d_in[4];
    const float* W2l = (const float*)d_in[5];
    const float* b2l = (const float*)d_in[6];
    const float* W2r = (const float*)d_in[7];
    const float* Wm1 = (const float*)d_in[8];
    const float* bm1 = (const float*)d_in[9];
    const float* Wm2 = (const float*)d_in[10];
    const float* bm2 = (const float*)d_in[11];

    char* ws = (char*)d_ws;
    unsigned short* PQ       = (unsigned short*)(ws);
    unsigned short* xb       = (unsigned short*)(ws);
    unsigned short* h1       = (unsigned short*)(ws + 12800000);
    unsigned short* aggb     = (unsigned short*)(ws + 25600000);
    unsigned short* wb       = (unsigned short*)(ws + 51200000);
    int*            s32      = (int*)(ws + 51462144);
    int*            d32      = (int*)(ws + 54662144);
    int*            deg      = (int*)(ws + 57862144);
    int*            rowstart = (int*)(ws + 58062208);
    int*            cursor   = (int*)(ws + 58262272);
    int*            nbr      = (int*)(ws + 58462336);
    int*            eid      = (int*)(ws + 61662336);
    unsigned short* h2       = (unsigned short*)(ws + 64862336);
    int*            exloc    = (int*)(ws + 77662336);
    int*            bsum     = (int*)(ws + 77867136);
    float*          outp     = (float*)d_out;

    const unsigned short* w1l_b = wb;
    const unsigned short* w1r_b = wb + 16384;
    const unsigned short* w2l_b = wb + 32768;
    const unsigned short* w2r_b = wb + 49152;
    const unsigned short* wm1_b = wb + 65536;

    // prep: casts + indices(+hist) + parallel scan + CSR fill
    cast_x_kernel<<<6250, 256, 0, stream>>>(x, xb);
    cast_w_kernel<<<128, 256, 0, stream>>>(W1l, W1r, W2l, W2r, Wm1, wb);
    hipMemsetAsync(deg, 0, 200064, stream);
    edge_cvt_hist_kernel<<<3125, 256, 0, stream>>>(ei, s32, d32, deg);
    scan_p1_kernel<<<50, 1024, 0, stream>>>(deg, exloc, bsum);
    scan_p2_kernel<<<1, 64, 0, stream>>>(bsum);
    scan_p3_kernel<<<50, 1024, 0, stream>>>(exloc, bsum, rowstart, cursor);
    fill_kernel<<<3125, 256, 0, stream>>>(s32, d32, cursor, nbr, eid);

    // layer 1
    agg_gather_kernel<<<12500, 256, 0, stream>>>(xb, nbr, rowstart, aggb);
    node_gemm_kernel<<<782, 256, 0, stream>>>(aggb, xb, w1l_b, w1r_b, b1l, h1);
    // layer 2
    agg_gather_kernel<<<12500, 256, 0, stream>>>(h1, nbr, rowstart, aggb);
    node_gemm_kernel<<<782, 256, 0, stream>>>(aggb, h1, w2l_b, w2r_b, b2l, h2);
    // edge MLP (decomposed)
    pq_gemm_kernel<<<3125, 256, 0, stream>>>(h2, wm1_b, bm1, PQ);
    edge_dot_kernel<<<12500, 256, 0, stream>>>(PQ, nbr, eid, rowstart, Wm2, bm2, outp);
}

// Round 13
// 436.059 us; speedup vs baseline: 1.0170x; 1.0170x over previous
//
#include <hip/hip_runtime.h>
#include <hip/hip_bf16.h>

// GraphNet: N=50000 nodes, F=128 feats, H=128, MH=256, E=800000 edges
// Inputs FP32; bf16 workspace copies for MFMA; fp32 MFMA accumulation.
// h-space is stored PERMUTED (pi: col' = (col%16)*8 + col/16) so node_gemm's epilogue is
// one 16B store per (node,r). W2l/W2r/Wm1 have k-dim pre-permuted by pi to compensate.
// Edge MLP decomposed: P=h2@W1s^T, Q=h2@W1d^T+bm1 (PQ col-permuted c*16+nt), then
// out[e]=relu(P[src]+Q[dst]).Wm2p + bm2 via per-edge dot.
#define NN 50000
#define F 128
#define EE 800000
#define MHD 256

typedef __attribute__((ext_vector_type(8))) short bf16x8;
typedef __attribute__((ext_vector_type(4))) float f32x4;

__device__ __forceinline__ float b2f(unsigned short u) {
    union { unsigned int i; float f; } v; v.i = ((unsigned)u) << 16; return v.f;
}
__device__ __forceinline__ unsigned short f2b(float f) {
    unsigned int x = __float_as_uint(f);
    unsigned int r = x + 0x7fffu + ((x >> 16) & 1u);   // RNE
    return (unsigned short)(r >> 16);
}

// ---------------- fp32 -> bf16 cast of x ----------------
__global__ __launch_bounds__(256) void cast_x_kernel(
    const float* __restrict__ in, unsigned short* __restrict__ out) {
    int i = (blockIdx.x * 256 + threadIdx.x) * 4;
    float4 v = *(const float4*)(in + i);
    ushort4 o; o.x = f2b(v.x); o.y = f2b(v.y); o.z = f2b(v.z); o.w = f2b(v.w);
    *(ushort4*)(out + i) = o;
}

// ---------------- weights fp32 -> bf16; W2l/W2r/Wm1 k-dim permuted by pi ----------------
// pi storage: out k' holds orig k = (k'%8)*16 + k'/8 (per 128-col block).
// wb elems: W1l@0, W1r@16384, W2lp@32768, W2rp@49152, Wm1p@65536 (65536, [256,256])
__global__ __launch_bounds__(256) void cast_w_kernel(
    const float* __restrict__ W1l, const float* __restrict__ W1r,
    const float* __restrict__ W2l, const float* __restrict__ W2r,
    const float* __restrict__ Wm1, unsigned short* __restrict__ wb) {
    int i = (blockIdx.x * 256 + threadIdx.x) * 4;        // 131072 elems / 4
    unsigned short o[4];
    if (i < 32768) {                                     // W1l | W1r straight copy
        const float* p = (i < 16384) ? (W1l + i) : (W1r + (i - 16384));
        float4 v = *(const float4*)p;
        o[0] = f2b(v.x); o[1] = f2b(v.y); o[2] = f2b(v.z); o[3] = f2b(v.w);
    } else if (i < 65536) {                              // W2lp | W2rp (k permuted)
        int local = i - 32768;
        const float* M = (local < 16384) ? W2l : W2r;
        int lm = local & 16383;
        int n = lm >> 7, kp = lm & 127;
#pragma unroll
        for (int t = 0; t < 4; t++) {
            int k = ((kp + t) & 7) * 16 + ((kp + t) >> 3);
            o[t] = f2b(M[n * 128 + k]);
        }
    } else {                                             // Wm1p (k permuted per 128-half)
        int local = i - 65536;
        int n = local >> 8, k2 = local & 255;
        int half = k2 >> 7, kp = k2 & 127;
#pragma unroll
        for (int t = 0; t < 4; t++) {
            int k = half * 128 + ((kp + t) & 7) * 16 + ((kp + t) >> 3);
            o[t] = f2b(Wm1[n * 256 + k]);
        }
    }
    *(ushort4*)(wb + i) = *(ushort4*)o;
}

// ---------------- edge_index canonicalize -> int32 src/dst + degree histogram ----------------
__global__ __launch_bounds__(256) void edge_cvt_hist_kernel(
    const int* __restrict__ ei, int* __restrict__ s32, int* __restrict__ d32,
    int* __restrict__ deg) {
    __shared__ int isI64;
    if (threadIdx.x == 0) {
        int z = 0;
        for (int i = 1; i < 128; i += 2) z |= ei[i];
        isI64 = (z == 0) ? 1 : 0;
    }
    __syncthreads();
    int e = blockIdx.x * 256 + threadIdx.x;
    if (e >= EE) return;
    int s, d;
    if (isI64) {
        const long long* e64 = (const long long*)ei;
        s = (int)e64[e];
        d = (int)e64[EE + e];
    } else {
        s = ei[e];
        d = ei[EE + e];
    }
    s32[e] = s;
    d32[e] = d;
    atomicAdd(&deg[d], 1);
}

// ---------------- device-wide exclusive scan of deg (2 kernels) ----------------
__global__ __launch_bounds__(1024) void scan_p1_kernel(
    const int* __restrict__ deg, int* __restrict__ exloc, int* __restrict__ bsum) {
    __shared__ int part[1024];
    int t = threadIdx.x, gid = blockIdx.x * 1024 + t;
    int v = (gid < NN) ? deg[gid] : 0;
    part[t] = v;
    __syncthreads();
    for (int off = 1; off < 1024; off <<= 1) {
        int u = (t >= off) ? part[t - off] : 0;
        __syncthreads();
        part[t] += u;
        __syncthreads();
    }
    exloc[gid] = part[t] - v;
    if (t == 1023) bsum[blockIdx.x] = part[t];
}

// p3: block offset computed in-kernel (sum of bsum[0..b)); writes rowstart + cursor.
__global__ __launch_bounds__(1024) void scan_p3_kernel(
    const int* __restrict__ exloc, const int* __restrict__ bsum,
    int* __restrict__ rowstart, int* __restrict__ cursor) {
    __shared__ int offs;
    if (threadIdx.x == 0) {
        int s = 0;
        for (int b = 0; b < blockIdx.x; b++) s += bsum[b];
        offs = s;
    }
    __syncthreads();
    int gid = blockIdx.x * 1024 + threadIdx.x;
    if (gid > NN) return;
    if (gid == NN) { rowstart[NN] = EE; return; }
    int r = exloc[gid] + offs;
    rowstart[gid] = r;
    cursor[gid] = r;
}

__global__ __launch_bounds__(256) void fill_kernel(
    const int* __restrict__ s32, const int* __restrict__ d32,
    int* __restrict__ cursor, int* __restrict__ nbr, int* __restrict__ eid) {
    int e = blockIdx.x * 256 + threadIdx.x;
    if (e < EE) {
        int p = atomicAdd(&cursor[d32[e]], 1);
        nbr[p] = s32[e];
        eid[p] = e;
    }
}

// ---------------- gather aggregation + mean ----------------
// One wave/node; 16 lanes x 16B per neighbor row; 4 / 2 / 1 loads-in-flight tiers.
__global__ __launch_bounds__(256) void agg_gather_kernel(
    const unsigned short* __restrict__ xin,
    const int* __restrict__ nbr, const int* __restrict__ rowstart,
    unsigned short* __restrict__ aggb) {
    int wave = threadIdx.x >> 6, lane = threadIdx.x & 63;
    int node = blockIdx.x * 4 + wave;
    if (node >= NN) return;
    int part = lane >> 4;
    int col8 = (lane & 15) * 8;
    int beg = rowstart[node], end = rowstart[node + 1];
    float a[8] = {0,0,0,0,0,0,0,0};
    float b[8] = {0,0,0,0,0,0,0,0};
    int j = beg + part;
    for (; j + 12 < end; j += 16) {          // 4 outstanding loads, 16 nbrs/wave-iter
        int s0 = nbr[j], s1 = nbr[j + 4], s2 = nbr[j + 8], s3 = nbr[j + 12];
        bf16x8 v0 = *(const bf16x8*)(xin + (size_t)s0 * F + col8);
        bf16x8 v1 = *(const bf16x8*)(xin + (size_t)s1 * F + col8);
        bf16x8 v2 = *(const bf16x8*)(xin + (size_t)s2 * F + col8);
        bf16x8 v3 = *(const bf16x8*)(xin + (size_t)s3 * F + col8);
        for (int i = 0; i < 8; i++) a[i] += b2f((unsigned short)v0[i]);
        for (int i = 0; i < 8; i++) b[i] += b2f((unsigned short)v1[i]);
        for (int i = 0; i < 8; i++) a[i] += b2f((unsigned short)v2[i]);
        for (int i = 0; i < 8; i++) b[i] += b2f((unsigned short)v3[i]);
    }
    for (; j + 4 < end; j += 8) {            // 2 outstanding loads (mid-degree tail)
        int s0 = nbr[j], s1 = nbr[j + 4];
        bf16x8 v0 = *(const bf16x8*)(xin + (size_t)s0 * F + col8);
        bf16x8 v1 = *(const bf16x8*)(xin + (size_t)s1 * F + col8);
        for (int i = 0; i < 8; i++) a[i] += b2f((unsigned short)v0[i]);
        for (int i = 0; i < 8; i++) b[i] += b2f((unsigned short)v1[i]);
    }
    if (j < end) {
        int s0 = nbr[j];
        bf16x8 v0 = *(const bf16x8*)(xin + (size_t)s0 * F + col8);
        for (int i = 0; i < 8; i++) a[i] += b2f((unsigned short)v0[i]);
    }
    float inv = 1.0f / fmaxf((float)(end - beg), 1.0f);
    unsigned short o[8];
    for (int i = 0; i < 8; i++) {
        float v = a[i] + b[i];
        v += __shfl_xor(v, 16);
        v += __shfl_xor(v, 32);
        o[i] = f2b(v * inv);
    }
    if (part == 0)
        *(bf16x8*)(aggb + (size_t)node * F + col8) = *(bf16x8*)o;
}

// ---------------- fused SAGE combine: out = relu(A1@W1^T + bias + A2@W2^T) ----------------
// Output stored in pi-space: col' = c*8+nt -> ONE bf16x8 store per (node,r), 256B/row
// coalesced. bias indexed by ORIGINAL col nt*16+c (identity unchanged).
__global__ __launch_bounds__(256) void node_gemm_kernel(
    const unsigned short* __restrict__ A1, const unsigned short* __restrict__ A2,
    const unsigned short* __restrict__ W1, const unsigned short* __restrict__ W2,
    const float* __restrict__ bias,
    unsigned short* __restrict__ out) {
    int wave = threadIdx.x >> 6, lane = threadIdx.x & 63;
    int c = lane & 15, q = lane >> 4;
    int m0 = (blockIdx.x * 4 + wave) * 16;
    if (m0 >= NN) return;
    f32x4 acc[8];
    for (int nt = 0; nt < 8; nt++) {
        float b = bias[nt * 16 + c];
        acc[nt] = (f32x4){b, b, b, b};
    }
    int mrow = m0 + c; if (mrow > NN - 1) mrow = NN - 1;
    for (int op = 0; op < 2; op++) {
        const unsigned short* ap = (op ? A2 : A1) + (size_t)mrow * F + q * 8;
        const unsigned short* W  = op ? W2 : W1;
        for (int kb = 0; kb < 4; kb++) {
            bf16x8 a = *(const bf16x8*)(ap + kb * 32);
            for (int nt = 0; nt < 8; nt++) {
                bf16x8 b = *(const bf16x8*)(W + (size_t)(nt * 16 + c) * F + kb * 32 + q * 8);
                acc[nt] = __builtin_amdgcn_mfma_f32_16x16x32_bf16(a, b, acc[nt], 0, 0, 0);
            }
        }
    }
#pragma unroll
    for (int r = 0; r < 4; r++) {
        int node = m0 + q * 4 + r;
        if (node < NN) {
            unsigned short o[8];
#pragma unroll
            for (int nt = 0; nt < 8; nt++) o[nt] = f2b(fmaxf(acc[nt][r], 0.0f));
            *(bf16x8*)(out + (size_t)node * F + c * 8) = *(bf16x8*)o;
        }
    }
}

// ---------------- PQ GEMM (wave-split N, permuted out cols): PQ[n] bf16 [N,512] ----------
// A = h2 (pi-space), B = Wm1p (k-dim pi-permuted) -> dot is exact.
__global__ __launch_bounds__(256) void pq_gemm_kernel(
    const unsigned short* __restrict__ h,
    const unsigned short* __restrict__ wmb,
    const float* __restrict__ bm1,
    unsigned short* __restrict__ PQ) {
    int wave = threadIdx.x >> 6, lane = threadIdx.x & 63;
    int c = lane & 15, q = lane >> 4;
    int half = wave >> 1, ntBase = (wave & 1) * 8;
    int m0 = blockIdx.x * 16;
    int mrow = m0 + c; if (mrow > NN - 1) mrow = NN - 1;
    bf16x8 a[4];
#pragma unroll
    for (int kb = 0; kb < 4; kb++)
        a[kb] = *(const bf16x8*)(h + (size_t)mrow * F + kb * 32 + q * 8);
    f32x4 acc[8];
#pragma unroll
    for (int nt = 0; nt < 8; nt++) {
        float b = half ? bm1[(ntBase + nt) * 16 + c] : 0.0f;
        acc[nt] = (f32x4){b, b, b, b};
    }
#pragma unroll
    for (int kb = 0; kb < 4; kb++) {
#pragma unroll
        for (int nt = 0; nt < 8; nt++) {
            bf16x8 b = *(const bf16x8*)(wmb + (size_t)((ntBase + nt) * 16 + c) * 256 + half * 128 + kb * 32 + q * 8);
            acc[nt] = __builtin_amdgcn_mfma_f32_16x16x32_bf16(a[kb], b, acc[nt], 0, 0, 0);
        }
    }
#pragma unroll
    for (int r = 0; r < 4; r++) {
        int node = m0 + q * 4 + r;
        if (node < NN) {
            unsigned short o[8];
#pragma unroll
            for (int nt = 0; nt < 8; nt++) o[nt] = f2b(acc[nt][r]);
            *(bf16x8*)(PQ + (size_t)node * 512 + half * 256 + c * 16 + ntBase) = *(bf16x8*)o;
        }
    }
}

// ---------------- edge dot: out[eid] = relu(P[src]+Q[dst]).Wm2p + bm2 ----------------
__global__ __launch_bounds__(256) void edge_dot_kernel(
    const unsigned short* __restrict__ PQ,
    const int* __restrict__ nbr, const int* __restrict__ eid,
    const int* __restrict__ rowstart,
    const float* __restrict__ Wm2, const float* __restrict__ bm2,
    float* __restrict__ out) {
    int wave = threadIdx.x >> 6, lane = threadIdx.x & 63;
    int node = blockIdx.x * 4 + wave;
    if (node >= NN) return;
    int g = lane >> 4, l16 = lane & 15;
    int col = l16 * 16;
    float w2f[16], qf[16];
#pragma unroll
    for (int i = 0; i < 16; i++) w2f[i] = Wm2[i * 16 + l16];   // inverse perm gather
    {
        bf16x8 q0 = *(const bf16x8*)(PQ + (size_t)node * 512 + 256 + col);
        bf16x8 q1 = *(const bf16x8*)(PQ + (size_t)node * 512 + 256 + col + 8);
#pragma unroll
        for (int i = 0; i < 8; i++) { qf[i] = b2f((unsigned short)q0[i]); qf[8 + i] = b2f((unsigned short)q1[i]); }
    }
    float b2 = bm2[0];
    int beg = rowstart[node], end = rowstart[node + 1];
    int j = beg + g;
    for (; j + 4 < end; j += 8) {
        int s0 = nbr[j], s1 = nbr[j + 4];
        int id0 = eid[j], id1 = eid[j + 4];
        uint4 a0 = *(const uint4*)(PQ + (size_t)s0 * 512 + col);
        uint4 a1 = *(const uint4*)(PQ + (size_t)s0 * 512 + col + 8);
        uint4 c0 = *(const uint4*)(PQ + (size_t)s1 * 512 + col);
        uint4 c1 = *(const uint4*)(PQ + (size_t)s1 * 512 + col + 8);
        float t0 = 0.f, t1 = 0.f;
        unsigned int w0[8] = {a0.x, a0.y, a0.z, a0.w, a1.x, a1.y, a1.z, a1.w};
        unsigned int w1[8] = {c0.x, c0.y, c0.z, c0.w, c1.x, c1.y, c1.z, c1.w};
#pragma unroll
        for (int i = 0; i < 8; i++) {
            float lo0 = __uint_as_float(w0[i] << 16);
            float hi0 = __uint_as_float(w0[i] & 0xffff0000u);
            float lo1 = __uint_as_float(w1[i] << 16);
            float hi1 = __uint_as_float(w1[i] & 0xffff0000u);
            t0 += fmaxf(lo0 + qf[2 * i], 0.f) * w2f[2 * i]
                + fmaxf(hi0 + qf[2 * i + 1], 0.f) * w2f[2 * i + 1];
            t1 += fmaxf(lo1 + qf[2 * i], 0.f) * w2f[2 * i]
                + fmaxf(hi1 + qf[2 * i + 1], 0.f) * w2f[2 * i + 1];
        }
        t0 += __shfl_xor(t0, 1);  t1 += __shfl_xor(t1, 1);
        t0 += __shfl_xor(t0, 2);  t1 += __shfl_xor(t1, 2);
        t0 += __shfl_xor(t0, 4);  t1 += __shfl_xor(t1, 4);
        t0 += __shfl_xor(t0, 8);  t1 += __shfl_xor(t1, 8);
        if (l16 == 0) { out[id0] = t0 + b2; out[id1] = t1 + b2; }
    }
    for (; j < end; j += 4) {
        int s = nbr[j];
        int id = eid[j];
        uint4 a0 = *(const uint4*)(PQ + (size_t)s * 512 + col);
        uint4 a1 = *(const uint4*)(PQ + (size_t)s * 512 + col + 8);
        unsigned int w0[8] = {a0.x, a0.y, a0.z, a0.w, a1.x, a1.y, a1.z, a1.w};
        float t = 0.f;
#pragma unroll
        for (int i = 0; i < 8; i++) {
            float lo = __uint_as_float(w0[i] << 16);
            float hi = __uint_as_float(w0[i] & 0xffff0000u);
            t += fmaxf(lo + qf[2 * i], 0.f) * w2f[2 * i]
               + fmaxf(hi + qf[2 * i + 1], 0.f) * w2f[2 * i + 1];
        }
        t += __shfl_xor(t, 1);
        t += __shfl_xor(t, 2);
        t += __shfl_xor(t, 4);
        t += __shfl_xor(t, 8);
        if (l16 == 0) out[id] = t + b2;
    }
}

extern "C" void kernel_launch(void* const* d_in, const int* in_sizes, int n_in,
                              void* d_out, int out_size, void* d_ws, size_t ws_size,
                              hipStream_t stream) {
    const float* x   = (const float*)d_in[0];
    const int*   ei  = (const int*)d_in[1];
    const float* W1l = (const float*)d_in[2];
    const float* b1l = (const float*)d_in[3];
    const float* W1r = (const float*)d_in[4];
    const float* W2l = (const float*)d_in[5];
    const float* b2l = (const float*)d_in[6];
    const float* W2r = (const float*)d_in[7];
    const float* Wm1 = (const float*)d_in[8];
    const float* bm1 = (const float*)d_in[9];
    const float* Wm2 = (const float*)d_in[10];
    const float* bm2 = (const float*)d_in[11];

    char* ws = (char*)d_ws;
    unsigned short* PQ       = (unsigned short*)(ws);
    unsigned short* xb       = (unsigned short*)(ws);
    unsigned short* h1       = (unsigned short*)(ws + 12800000);
    unsigned short* aggb     = (unsigned short*)(ws + 25600000);
    unsigned short* wb       = (unsigned short*)(ws + 51200000);
    int*            s32      = (int*)(ws + 51462144);
    int*            d32      = (int*)(ws + 54662144);
    int*            deg      = (int*)(ws + 57862144);
    int*            rowstart = (int*)(ws + 58062208);
    int*            cursor   = (int*)(ws + 58262272);
    int*            nbr      = (int*)(ws + 58462336);
    int*            eid      = (int*)(ws + 61662336);
    unsigned short* h2       = (unsigned short*)(ws + 64862336);
    int*            exloc    = (int*)(ws + 77662336);
    int*            bsum     = (int*)(ws + 77867136);
    float*          outp     = (float*)d_out;

    const unsigned short* w1l_b  = wb;
    const unsigned short* w1r_b  = wb + 16384;
    const unsigned short* w2l_p  = wb + 32768;
    const unsigned short* w2r_p  = wb + 49152;
    const unsigned short* wm1_p  = wb + 65536;

    // prep: casts(+k-permutes) + indices(+hist) + parallel scan + CSR fill
    cast_x_kernel<<<6250, 256, 0, stream>>>(x, xb);
    cast_w_kernel<<<128, 256, 0, stream>>>(W1l, W1r, W2l, W2r, Wm1, wb);
    hipMemsetAsync(deg, 0, 200064, stream);
    edge_cvt_hist_kernel<<<3125, 256, 0, stream>>>(ei, s32, d32, deg);
    scan_p1_kernel<<<50, 1024, 0, stream>>>(deg, exloc, bsum);
    scan_p3_kernel<<<50, 1024, 0, stream>>>(exloc, bsum, rowstart, cursor);
    fill_kernel<<<3125, 256, 0, stream>>>(s32, d32, cursor, nbr, eid);

    // layer 1 (x unpermuted in, h1 pi-space out)
    agg_gather_kernel<<<12500, 256, 0, stream>>>(xb, nbr, rowstart, aggb);
    node_gemm_kernel<<<782, 256, 0, stream>>>(aggb, xb, w1l_b, w1r_b, b1l, h1);
    // layer 2 (h1 pi-space in with k-permuted W2, h2 pi-space out)
    agg_gather_kernel<<<12500, 256, 0, stream>>>(h1, nbr, rowstart, aggb);
    node_gemm_kernel<<<782, 256, 0, stream>>>(aggb, h1, w2l_p, w2r_p, b2l, h2);
    // edge MLP (decomposed; Wm1 k-permuted to match h2 pi-space)
    pq_gemm_kernel<<<3125, 256, 0, stream>>>(h2, wm1_p, bm1, PQ);
    edge_dot_kernel<<<12500, 256, 0, stream>>>(PQ, nbr, eid, rowstart, Wm2, bm2, outp);
}

// Round 15
// 434.334 us; speedup vs baseline: 1.0211x; 1.0040x over previous
//
#include <hip/hip_runtime.h>
#include <hip/hip_bf16.h>

// GraphNet: N=50000 nodes, F=128 feats, H=128, MH=256, E=800000 edges
// Inputs FP32; bf16 workspace copies for MFMA; fp32 MFMA accumulation.
// h-space stored PERMUTED (pi: col' = (col%16)*8 + col/16); W2l/W2r/Wm1 k-dim pre-permuted.
// SAGE layer FUSED: waves aggregate 64 nodes into LDS, __syncthreads (REQUIRED: cross-lane
// LDS visibility is not ordered by per-thread dataflow — R14 bug), then MFMA combine.
// Edge MLP decomposed: P=h2@W1s^T, Q=h2@W1d^T+bm1 (PQ col-permuted c*16+nt), then
// out[e]=relu(P[src]+Q[dst]).Wm2p + bm2 via per-edge dot.
#define NN 50000
#define F 128
#define EE 800000
#define MHD 256

typedef __attribute__((ext_vector_type(8))) short bf16x8;
typedef __attribute__((ext_vector_type(4))) float f32x4;

__device__ __forceinline__ float b2f(unsigned short u) {
    union { unsigned int i; float f; } v; v.i = ((unsigned)u) << 16; return v.f;
}
__device__ __forceinline__ unsigned short f2b(float f) {
    unsigned int x = __float_as_uint(f);
    unsigned int r = x + 0x7fffu + ((x >> 16) & 1u);   // RNE
    return (unsigned short)(r >> 16);
}

// ---------------- fp32 -> bf16 cast of x ----------------
__global__ __launch_bounds__(256) void cast_x_kernel(
    const float* __restrict__ in, unsigned short* __restrict__ out) {
    int i = (blockIdx.x * 256 + threadIdx.x) * 4;
    float4 v = *(const float4*)(in + i);
    ushort4 o; o.x = f2b(v.x); o.y = f2b(v.y); o.z = f2b(v.z); o.w = f2b(v.w);
    *(ushort4*)(out + i) = o;
}

// ---------------- weights fp32 -> bf16; W2l/W2r/Wm1 k-dim permuted by pi ----------------
// wb elems: W1l@0, W1r@16384, W2lp@32768, W2rp@49152, Wm1p@65536 (65536, [256,256])
__global__ __launch_bounds__(256) void cast_w_kernel(
    const float* __restrict__ W1l, const float* __restrict__ W1r,
    const float* __restrict__ W2l, const float* __restrict__ W2r,
    const float* __restrict__ Wm1, unsigned short* __restrict__ wb) {
    int i = (blockIdx.x * 256 + threadIdx.x) * 4;        // 131072 elems / 4
    unsigned short o[4];
    if (i < 32768) {                                     // W1l | W1r straight copy
        const float* p = (i < 16384) ? (W1l + i) : (W1r + (i - 16384));
        float4 v = *(const float4*)p;
        o[0] = f2b(v.x); o[1] = f2b(v.y); o[2] = f2b(v.z); o[3] = f2b(v.w);
    } else if (i < 65536) {                              // W2lp | W2rp (k permuted)
        int local = i - 32768;
        const float* M = (local < 16384) ? W2l : W2r;
        int lm = local & 16383;
        int n = lm >> 7, kp = lm & 127;
#pragma unroll
        for (int t = 0; t < 4; t++) {
            int k = ((kp + t) & 7) * 16 + ((kp + t) >> 3);
            o[t] = f2b(M[n * 128 + k]);
        }
    } else {                                             // Wm1p (k permuted per 128-half)
        int local = i - 65536;
        int n = local >> 8, k2 = local & 255;
        int half = k2 >> 7, kp = k2 & 127;
#pragma unroll
        for (int t = 0; t < 4; t++) {
            int k = half * 128 + ((kp + t) & 7) * 16 + ((kp + t) >> 3);
            o[t] = f2b(Wm1[n * 256 + k]);
        }
    }
    *(ushort4*)(wb + i) = *(ushort4*)o;
}

// ---------------- edge_index canonicalize -> int32 src/dst + degree histogram ----------------
__global__ __launch_bounds__(256) void edge_cvt_hist_kernel(
    const int* __restrict__ ei, int* __restrict__ s32, int* __restrict__ d32,
    int* __restrict__ deg) {
    __shared__ int isI64;
    if (threadIdx.x == 0) {
        int z = 0;
        for (int i = 1; i < 128; i += 2) z |= ei[i];
        isI64 = (z == 0) ? 1 : 0;
    }
    __syncthreads();
    int e = blockIdx.x * 256 + threadIdx.x;
    if (e >= EE) return;
    int s, d;
    if (isI64) {
        const long long* e64 = (const long long*)ei;
        s = (int)e64[e];
        d = (int)e64[EE + e];
    } else {
        s = ei[e];
        d = ei[EE + e];
    }
    s32[e] = s;
    d32[e] = d;
    atomicAdd(&deg[d], 1);
}

// ---------------- device-wide exclusive scan of deg (2 kernels) ----------------
__global__ __launch_bounds__(1024) void scan_p1_kernel(
    const int* __restrict__ deg, int* __restrict__ exloc, int* __restrict__ bsum) {
    __shared__ int part[1024];
    int t = threadIdx.x, gid = blockIdx.x * 1024 + t;
    int v = (gid < NN) ? deg[gid] : 0;
    part[t] = v;
    __syncthreads();
    for (int off = 1; off < 1024; off <<= 1) {
        int u = (t >= off) ? part[t - off] : 0;
        __syncthreads();
        part[t] += u;
        __syncthreads();
    }
    exloc[gid] = part[t] - v;
    if (t == 1023) bsum[blockIdx.x] = part[t];
}

__global__ __launch_bounds__(1024) void scan_p3_kernel(
    const int* __restrict__ exloc, const int* __restrict__ bsum,
    int* __restrict__ rowstart, int* __restrict__ cursor) {
    __shared__ int offs;
    if (threadIdx.x == 0) {
        int s = 0;
        for (int b = 0; b < blockIdx.x; b++) s += bsum[b];
        offs = s;
    }
    __syncthreads();
    int gid = blockIdx.x * 1024 + threadIdx.x;
    if (gid > NN) return;
    if (gid == NN) { rowstart[NN] = EE; return; }
    int r = exloc[gid] + offs;
    rowstart[gid] = r;
    cursor[gid] = r;
}

__global__ __launch_bounds__(256) void fill_kernel(
    const int* __restrict__ s32, const int* __restrict__ d32,
    int* __restrict__ cursor, int* __restrict__ nbr, int* __restrict__ eid) {
    int e = blockIdx.x * 256 + threadIdx.x;
    if (e < EE) {
        int p = atomicAdd(&cursor[d32[e]], 1);
        nbr[p] = s32[e];
        eid[p] = e;
    }
}

// ---------------- FUSED SAGE layer: aggregate + combine ----------------
// Block 256 thr = 4 waves, 64 nodes. Wave aggregates its 16 nodes into its LDS slice
// (4 node-groups x 16 lanes, x4 neighbor unroll -> 16 loads in flight), then
// __syncthreads (cross-lane LDS visibility), then MFMA combine with pi-store epilogue.
// NO early return: all waves must reach the barrier (inactive waves do guarded no-ops).
__global__ __launch_bounds__(256) void sage_layer_kernel(
    const unsigned short* __restrict__ xin,
    const int* __restrict__ nbr, const int* __restrict__ rowstart,
    const unsigned short* __restrict__ W1, const unsigned short* __restrict__ W2,
    const float* __restrict__ bias,
    unsigned short* __restrict__ out) {
    __shared__ unsigned short lds[4][16][136];
    int wave = threadIdx.x >> 6, lane = threadIdx.x & 63;
    int m0 = (blockIdx.x * 4 + wave) * 16;

    // ---- Phase A: aggregate 16 nodes, 4 at a time ----
    int g = lane >> 4, l16 = lane & 15, col8 = l16 * 8;
    for (int batch = 0; batch < 4; batch++) {
        int node = m0 + batch * 4 + g;
        int beg = 0, end = 0;
        if (node < NN) { beg = rowstart[node]; end = rowstart[node + 1]; }
        float a[8] = {0,0,0,0,0,0,0,0};
        int j = beg;
        for (; j + 3 < end; j += 4) {
            int s0 = nbr[j], s1 = nbr[j + 1], s2 = nbr[j + 2], s3 = nbr[j + 3];
            bf16x8 v0 = *(const bf16x8*)(xin + (size_t)s0 * F + col8);
            bf16x8 v1 = *(const bf16x8*)(xin + (size_t)s1 * F + col8);
            bf16x8 v2 = *(const bf16x8*)(xin + (size_t)s2 * F + col8);
            bf16x8 v3 = *(const bf16x8*)(xin + (size_t)s3 * F + col8);
            for (int i = 0; i < 8; i++)
                a[i] += (b2f((unsigned short)v0[i]) + b2f((unsigned short)v1[i]))
                      + (b2f((unsigned short)v2[i]) + b2f((unsigned short)v3[i]));
        }
        for (; j < end; j++) {
            int s0 = nbr[j];
            bf16x8 v0 = *(const bf16x8*)(xin + (size_t)s0 * F + col8);
            for (int i = 0; i < 8; i++) a[i] += b2f((unsigned short)v0[i]);
        }
        float inv = 1.0f / fmaxf((float)(end - beg), 1.0f);
        unsigned short o[8];
        for (int i = 0; i < 8; i++) o[i] = f2b(a[i] * inv);
        *(bf16x8*)&lds[wave][batch * 4 + g][col8] = *(bf16x8*)o;
    }
    __syncthreads();   // REQUIRED: cross-lane LDS visibility (R14 omitted -> garbage)

    // ---- Phase B: combine out = relu(agg@W1^T + bias + root@W2^T) ----
    int c = lane & 15, q = lane >> 4;
    f32x4 acc[8];
    for (int nt = 0; nt < 8; nt++) {
        float b = bias[nt * 16 + c];
        acc[nt] = (f32x4){b, b, b, b};
    }
    int mrow = m0 + c; if (mrow > NN - 1) mrow = NN - 1;
    for (int op = 0; op < 2; op++) {
        const unsigned short* W = op ? W2 : W1;
        for (int kb = 0; kb < 4; kb++) {
            bf16x8 a;
            if (op == 0) a = *(const bf16x8*)&lds[wave][c][kb * 32 + q * 8];
            else         a = *(const bf16x8*)(xin + (size_t)mrow * F + kb * 32 + q * 8);
            for (int nt = 0; nt < 8; nt++) {
                bf16x8 b = *(const bf16x8*)(W + (size_t)(nt * 16 + c) * F + kb * 32 + q * 8);
                acc[nt] = __builtin_amdgcn_mfma_f32_16x16x32_bf16(a, b, acc[nt], 0, 0, 0);
            }
        }
    }
#pragma unroll
    for (int r = 0; r < 4; r++) {
        int node = m0 + q * 4 + r;
        if (node < NN) {
            unsigned short o[8];
#pragma unroll
            for (int nt = 0; nt < 8; nt++) o[nt] = f2b(fmaxf(acc[nt][r], 0.0f));
            *(bf16x8*)(out + (size_t)node * F + c * 8) = *(bf16x8*)o;
        }
    }
}

// ---------------- PQ GEMM (wave-split N, permuted out cols): PQ[n] bf16 [N,512] ----------
__global__ __launch_bounds__(256) void pq_gemm_kernel(
    const unsigned short* __restrict__ h,
    const unsigned short* __restrict__ wmb,
    const float* __restrict__ bm1,
    unsigned short* __restrict__ PQ) {
    int wave = threadIdx.x >> 6, lane = threadIdx.x & 63;
    int c = lane & 15, q = lane >> 4;
    int half = wave >> 1, ntBase = (wave & 1) * 8;
    int m0 = blockIdx.x * 16;
    int mrow = m0 + c; if (mrow > NN - 1) mrow = NN - 1;
    bf16x8 a[4];
#pragma unroll
    for (int kb = 0; kb < 4; kb++)
        a[kb] = *(const bf16x8*)(h + (size_t)mrow * F + kb * 32 + q * 8);
    f32x4 acc[8];
#pragma unroll
    for (int nt = 0; nt < 8; nt++) {
        float b = half ? bm1[(ntBase + nt) * 16 + c] : 0.0f;
        acc[nt] = (f32x4){b, b, b, b};
    }
#pragma unroll
    for (int kb = 0; kb < 4; kb++) {
#pragma unroll
        for (int nt = 0; nt < 8; nt++) {
            bf16x8 b = *(const bf16x8*)(wmb + (size_t)((ntBase + nt) * 16 + c) * 256 + half * 128 + kb * 32 + q * 8);
            acc[nt] = __builtin_amdgcn_mfma_f32_16x16x32_bf16(a[kb], b, acc[nt], 0, 0, 0);
        }
    }
#pragma unroll
    for (int r = 0; r < 4; r++) {
        int node = m0 + q * 4 + r;
        if (node < NN) {
            unsigned short o[8];
#pragma unroll
            for (int nt = 0; nt < 8; nt++) o[nt] = f2b(acc[nt][r]);
            *(bf16x8*)(PQ + (size_t)node * 512 + half * 256 + c * 16 + ntBase) = *(bf16x8*)o;
        }
    }
}

// ---------------- edge dot: out[eid] = relu(P[src]+Q[dst]).Wm2p + bm2 ----------------
__global__ __launch_bounds__(256) void edge_dot_kernel(
    const unsigned short* __restrict__ PQ,
    const int* __restrict__ nbr, const int* __restrict__ eid,
    const int* __restrict__ rowstart,
    const float* __restrict__ Wm2, const float* __restrict__ bm2,
    float* __restrict__ out) {
    int wave = threadIdx.x >> 6, lane = threadIdx.x & 63;
    int node = blockIdx.x * 4 + wave;
    if (node >= NN) return;
    int g = lane >> 4, l16 = lane & 15;
    int col = l16 * 16;
    float w2f[16], qf[16];
#pragma unroll
    for (int i = 0; i < 16; i++) w2f[i] = Wm2[i * 16 + l16];   // inverse perm gather
    {
        bf16x8 q0 = *(const bf16x8*)(PQ + (size_t)node * 512 + 256 + col);
        bf16x8 q1 = *(const bf16x8*)(PQ + (size_t)node * 512 + 256 + col + 8);
#pragma unroll
        for (int i = 0; i < 8; i++) { qf[i] = b2f((unsigned short)q0[i]); qf[8 + i] = b2f((unsigned short)q1[i]); }
    }
    float b2 = bm2[0];
    int beg = rowstart[node], end = rowstart[node + 1];
    int j = beg + g;
    for (; j + 4 < end; j += 8) {
        int s0 = nbr[j], s1 = nbr[j + 4];
        int id0 = eid[j], id1 = eid[j + 4];
        uint4 a0 = *(const uint4*)(PQ + (size_t)s0 * 512 + col);
        uint4 a1 = *(const uint4*)(PQ + (size_t)s0 * 512 + col + 8);
        uint4 c0 = *(const uint4*)(PQ + (size_t)s1 * 512 + col);
        uint4 c1 = *(const uint4*)(PQ + (size_t)s1 * 512 + col + 8);
        float t0 = 0.f, t1 = 0.f;
        unsigned int w0[8] = {a0.x, a0.y, a0.z, a0.w, a1.x, a1.y, a1.z, a1.w};
        unsigned int w1[8] = {c0.x, c0.y, c0.z, c0.w, c1.x, c1.y, c1.z, c1.w};
#pragma unroll
        for (int i = 0; i < 8; i++) {
            float lo0 = __uint_as_float(w0[i] << 16);
            float hi0 = __uint_as_float(w0[i] & 0xffff0000u);
            float lo1 = __uint_as_float(w1[i] << 16);
            float hi1 = __uint_as_float(w1[i] & 0xffff0000u);
            t0 += fmaxf(lo0 + qf[2 * i], 0.f) * w2f[2 * i]
                + fmaxf(hi0 + qf[2 * i + 1], 0.f) * w2f[2 * i + 1];
            t1 += fmaxf(lo1 + qf[2 * i], 0.f) * w2f[2 * i]
                + fmaxf(hi1 + qf[2 * i + 1], 0.f) * w2f[2 * i + 1];
        }
        t0 += __shfl_xor(t0, 1);  t1 += __shfl_xor(t1, 1);
        t0 += __shfl_xor(t0, 2);  t1 += __shfl_xor(t1, 2);
        t0 += __shfl_xor(t0, 4);  t1 += __shfl_xor(t1, 4);
        t0 += __shfl_xor(t0, 8);  t1 += __shfl_xor(t1, 8);
        if (l16 == 0) { out[id0] = t0 + b2; out[id1] = t1 + b2; }
    }
    for (; j < end; j += 4) {
        int s = nbr[j];
        int id = eid[j];
        uint4 a0 = *(const uint4*)(PQ + (size_t)s * 512 + col);
        uint4 a1 = *(const uint4*)(PQ + (size_t)s * 512 + col + 8);
        unsigned int w0[8] = {a0.x, a0.y, a0.z, a0.w, a1.x, a1.y, a1.z, a1.w};
        float t = 0.f;
#pragma unroll
        for (int i = 0; i < 8; i++) {
            float lo = __uint_as_float(w0[i] << 16);
            float hi = __uint_as_float(w0[i] & 0xffff0000u);
            t += fmaxf(lo + qf[2 * i], 0.f) * w2f[2 * i]
               + fmaxf(hi + qf[2 * i + 1], 0.f) * w2f[2 * i + 1];
        }
        t += __shfl_xor(t, 1);
        t += __shfl_xor(t, 2);
        t += __shfl_xor(t, 4);
        t += __shfl_xor(t, 8);
        if (l16 == 0) out[id] = t + b2;
    }
}

extern "C" void kernel_launch(void* const* d_in, const int* in_sizes, int n_in,
                              void* d_out, int out_size, void* d_ws, size_t ws_size,
                              hipStream_t stream) {
    const float* x   = (const float*)d_in[0];
    const int*   ei  = (const int*)d_in[1];
    const float* W1l = (const float*)d_in[2];
    const float* b1l = (const float*)d_in[3];
    const float* W1r = (const float*)d_in[4];
    const float* W2l = (const float*)d_in[5];
    const float* b2l = (const float*)d_in[6];
    const float* W2r = (const float*)d_in[7];
    const float* Wm1 = (const float*)d_in[8];
    const float* bm1 = (const float*)d_in[9];
    const float* Wm2 = (const float*)d_in[10];
    const float* bm2 = (const float*)d_in[11];

    char* ws = (char*)d_ws;
    unsigned short* PQ       = (unsigned short*)(ws);
    unsigned short* xb       = (unsigned short*)(ws);
    unsigned short* h1       = (unsigned short*)(ws + 12800000);
    unsigned short* wb       = (unsigned short*)(ws + 51200000);
    int*            s32      = (int*)(ws + 51462144);
    int*            d32      = (int*)(ws + 54662144);
    int*            deg      = (int*)(ws + 57862144);
    int*            rowstart = (int*)(ws + 58062208);
    int*            cursor   = (int*)(ws + 58262272);
    int*            nbr      = (int*)(ws + 58462336);
    int*            eid      = (int*)(ws + 61662336);
    unsigned short* h2       = (unsigned short*)(ws + 64862336);
    int*            exloc    = (int*)(ws + 77662336);
    int*            bsum     = (int*)(ws + 77867136);
    float*          outp     = (float*)d_out;

    const unsigned short* w1l_b  = wb;
    const unsigned short* w1r_b  = wb + 16384;
    const unsigned short* w2l_p  = wb + 32768;
    const unsigned short* w2r_p  = wb + 49152;
    const unsigned short* wm1_p  = wb + 65536;

    // prep: casts(+k-permutes) + indices(+hist) + parallel scan + CSR fill
    cast_x_kernel<<<6250, 256, 0, stream>>>(x, xb);
    cast_w_kernel<<<128, 256, 0, stream>>>(W1l, W1r, W2l, W2r, Wm1, wb);
    hipMemsetAsync(deg, 0, 200064, stream);
    edge_cvt_hist_kernel<<<3125, 256, 0, stream>>>(ei, s32, d32, deg);
    scan_p1_kernel<<<50, 1024, 0, stream>>>(deg, exloc, bsum);
    scan_p3_kernel<<<50, 1024, 0, stream>>>(exloc, bsum, rowstart, cursor);
    fill_kernel<<<3125, 256, 0, stream>>>(s32, d32, cursor, nbr, eid);

    // layer 1 (fused agg+combine; x unpermuted in, h1 pi-space out)
    sage_layer_kernel<<<782, 256, 0, stream>>>(xb, nbr, rowstart, w1l_b, w1r_b, b1l, h1);
    // layer 2 (h1 pi-space in with k-permuted W2, h2 pi-space out)
    sage_layer_kernel<<<782, 256, 0, stream>>>(h1, nbr, rowstart, w2l_p, w2r_p, b2l, h2);
    // edge MLP (decomposed; Wm1 k-permuted to match h2 pi-space)
    pq_gemm_kernel<<<3125, 256, 0, stream>>>(h2, wm1_p, bm1, PQ);
    edge_dot_kernel<<<12500, 256, 0, stream>>>(PQ, nbr, eid, rowstart, Wm2, bm2, outp);
}

// Round 16
// 427.049 us; speedup vs baseline: 1.0385x; 1.0171x over previous
//
#include <hip/hip_runtime.h>
#include <hip/hip_bf16.h>

// GraphNet: N=50000 nodes, F=128 feats, H=128, MH=256, E=800000 edges
// Inputs FP32; bf16 workspace copies for MFMA; fp32 MFMA accumulation.
// h-space stored PERMUTED (pi: col' = (col%16)*8 + col/16); W2l/W2r/Wm1 k-dim pre-permuted.
// SAGE layer FUSED: waves aggregate into LDS (8 loads in flight/lane), __syncthreads,
// MFMA combine. CSR stores (src,eid) PACKED as int2 (one 8B scatter store in fill).
// Edge MLP decomposed: P=h2@W1s^T, Q=h2@W1d^T+bm1 (PQ col-permuted c*16+nt), then
// out[e]=relu(P[src]+Q[dst]).Wm2p + bm2 via per-edge dot.
#define NN 50000
#define F 128
#define EE 800000
#define MHD 256

typedef __attribute__((ext_vector_type(8))) short bf16x8;
typedef __attribute__((ext_vector_type(4))) float f32x4;

__device__ __forceinline__ float b2f(unsigned short u) {
    union { unsigned int i; float f; } v; v.i = ((unsigned)u) << 16; return v.f;
}
__device__ __forceinline__ unsigned short f2b(float f) {
    unsigned int x = __float_as_uint(f);
    unsigned int r = x + 0x7fffu + ((x >> 16) & 1u);   // RNE
    return (unsigned short)(r >> 16);
}

// ---------------- combined prep: cast x (6250 blk) | cast+permute W (128 blk) | zero deg (49 blk)
__global__ __launch_bounds__(256) void cast_zero_kernel(
    const float* __restrict__ x,
    const float* __restrict__ W1l, const float* __restrict__ W1r,
    const float* __restrict__ W2l, const float* __restrict__ W2r,
    const float* __restrict__ Wm1,
    unsigned short* __restrict__ xb, unsigned short* __restrict__ wb,
    int* __restrict__ deg) {
    int bid = blockIdx.x;
    if (bid < 6250) {
        int i = (bid * 256 + threadIdx.x) * 4;
        float4 v = *(const float4*)(x + i);
        ushort4 o; o.x = f2b(v.x); o.y = f2b(v.y); o.z = f2b(v.z); o.w = f2b(v.w);
        *(ushort4*)(xb + i) = o;
    } else if (bid < 6378) {
        int i = ((bid - 6250) * 256 + threadIdx.x) * 4;  // 131072 elems / 4
        unsigned short o[4];
        if (i < 32768) {                                 // W1l | W1r straight copy
            const float* p = (i < 16384) ? (W1l + i) : (W1r + (i - 16384));
            float4 v = *(const float4*)p;
            o[0] = f2b(v.x); o[1] = f2b(v.y); o[2] = f2b(v.z); o[3] = f2b(v.w);
        } else if (i < 65536) {                          // W2lp | W2rp (k permuted)
            int local = i - 32768;
            const float* M = (local < 16384) ? W2l : W2r;
            int lm = local & 16383;
            int n = lm >> 7, kp = lm & 127;
#pragma unroll
            for (int t = 0; t < 4; t++) {
                int k = ((kp + t) & 7) * 16 + ((kp + t) >> 3);
                o[t] = f2b(M[n * 128 + k]);
            }
        } else {                                         // Wm1p (k permuted per 128-half)
            int local = i - 65536;
            int n = local >> 8, k2 = local & 255;
            int half = k2 >> 7, kp = k2 & 127;
#pragma unroll
            for (int t = 0; t < 4; t++) {
                int k = half * 128 + ((kp + t) & 7) * 16 + ((kp + t) >> 3);
                o[t] = f2b(Wm1[n * 256 + k]);
            }
        }
        *(ushort4*)(wb + i) = *(ushort4*)o;
    } else {
        int idx = ((bid - 6378) * 256 + threadIdx.x) * 4;
        if (idx < 50016) *(int4*)(deg + idx) = (int4){0, 0, 0, 0};
    }
}

// ---------------- edge_index canonicalize -> int32 src/dst + degree histogram ----------------
__global__ __launch_bounds__(256) void edge_cvt_hist_kernel(
    const int* __restrict__ ei, int* __restrict__ s32, int* __restrict__ d32,
    int* __restrict__ deg) {
    __shared__ int isI64;
    if (threadIdx.x == 0) {
        int z = 0;
        for (int i = 1; i < 128; i += 2) z |= ei[i];
        isI64 = (z == 0) ? 1 : 0;
    }
    __syncthreads();
    int e = blockIdx.x * 256 + threadIdx.x;
    if (e >= EE) return;
    int s, d;
    if (isI64) {
        const long long* e64 = (const long long*)ei;
        s = (int)e64[e];
        d = (int)e64[EE + e];
    } else {
        s = ei[e];
        d = ei[EE + e];
    }
    s32[e] = s;
    d32[e] = d;
    atomicAdd(&deg[d], 1);
}

// ---------------- device-wide exclusive scan of deg (2 kernels) ----------------
__global__ __launch_bounds__(1024) void scan_p1_kernel(
    const int* __restrict__ deg, int* __restrict__ exloc, int* __restrict__ bsum) {
    __shared__ int part[1024];
    int t = threadIdx.x, gid = blockIdx.x * 1024 + t;
    int v = (gid < NN) ? deg[gid] : 0;
    part[t] = v;
    __syncthreads();
    for (int off = 1; off < 1024; off <<= 1) {
        int u = (t >= off) ? part[t - off] : 0;
        __syncthreads();
        part[t] += u;
        __syncthreads();
    }
    exloc[gid] = part[t] - v;
    if (t == 1023) bsum[blockIdx.x] = part[t];
}

__global__ __launch_bounds__(1024) void scan_p3_kernel(
    const int* __restrict__ exloc, const int* __restrict__ bsum,
    int* __restrict__ rowstart, int* __restrict__ cursor) {
    __shared__ int offs;
    if (threadIdx.x == 0) {
        int s = 0;
        for (int b = 0; b < blockIdx.x; b++) s += bsum[b];
        offs = s;
    }
    __syncthreads();
    int gid = blockIdx.x * 1024 + threadIdx.x;
    if (gid > NN) return;
    if (gid == NN) { rowstart[NN] = EE; return; }
    int r = exloc[gid] + offs;
    rowstart[gid] = r;
    cursor[gid] = r;
}

// ---------------- CSR fill: one packed 8B store per edge ----------------
__global__ __launch_bounds__(256) void fill_kernel(
    const int* __restrict__ s32, const int* __restrict__ d32,
    int* __restrict__ cursor, int2* __restrict__ nedge) {
    int e = blockIdx.x * 256 + threadIdx.x;
    if (e < EE) {
        int p = atomicAdd(&cursor[d32[e]], 1);
        nedge[p] = make_int2(s32[e], e);
    }
}

// ---------------- FUSED SAGE layer: aggregate + combine ----------------
// Block 256 thr = 4 waves, 64 nodes. Phase A: wave aggregates its 16 nodes (4 groups x 16
// lanes), neighbor loop unrolled x8 -> 8x16B loads in flight per lane; mean to LDS
// (stride 136). __syncthreads (cross-lane LDS visibility — R14 bug). Phase B: MFMA
// combine with pi-space 16B-store epilogue. No early return (all waves reach barrier).
__global__ __launch_bounds__(256) void sage_layer_kernel(
    const unsigned short* __restrict__ xin,
    const int2* __restrict__ nedge, const int* __restrict__ rowstart,
    const unsigned short* __restrict__ W1, const unsigned short* __restrict__ W2,
    const float* __restrict__ bias,
    unsigned short* __restrict__ out) {
    __shared__ unsigned short lds[4][16][136];
    int wave = threadIdx.x >> 6, lane = threadIdx.x & 63;
    int m0 = (blockIdx.x * 4 + wave) * 16;

    // ---- Phase A ----
    int g = lane >> 4, l16 = lane & 15, col8 = l16 * 8;
    for (int batch = 0; batch < 4; batch++) {
        int node = m0 + batch * 4 + g;
        int beg = 0, end = 0;
        if (node < NN) { beg = rowstart[node]; end = rowstart[node + 1]; }
        float a[8] = {0,0,0,0,0,0,0,0};
        float b[8] = {0,0,0,0,0,0,0,0};
        int j = beg;
        for (; j + 7 < end; j += 8) {        // 8 loads in flight
            int s0 = nedge[j].x,     s1 = nedge[j + 1].x, s2 = nedge[j + 2].x, s3 = nedge[j + 3].x;
            int s4 = nedge[j + 4].x, s5 = nedge[j + 5].x, s6 = nedge[j + 6].x, s7 = nedge[j + 7].x;
            bf16x8 v0 = *(const bf16x8*)(xin + (size_t)s0 * F + col8);
            bf16x8 v1 = *(const bf16x8*)(xin + (size_t)s1 * F + col8);
            bf16x8 v2 = *(const bf16x8*)(xin + (size_t)s2 * F + col8);
            bf16x8 v3 = *(const bf16x8*)(xin + (size_t)s3 * F + col8);
            bf16x8 v4 = *(const bf16x8*)(xin + (size_t)s4 * F + col8);
            bf16x8 v5 = *(const bf16x8*)(xin + (size_t)s5 * F + col8);
            bf16x8 v6 = *(const bf16x8*)(xin + (size_t)s6 * F + col8);
            bf16x8 v7 = *(const bf16x8*)(xin + (size_t)s7 * F + col8);
            for (int i = 0; i < 8; i++)
                a[i] += (b2f((unsigned short)v0[i]) + b2f((unsigned short)v1[i]))
                      + (b2f((unsigned short)v2[i]) + b2f((unsigned short)v3[i]));
            for (int i = 0; i < 8; i++)
                b[i] += (b2f((unsigned short)v4[i]) + b2f((unsigned short)v5[i]))
                      + (b2f((unsigned short)v6[i]) + b2f((unsigned short)v7[i]));
        }
        for (; j + 3 < end; j += 4) {
            int s0 = nedge[j].x, s1 = nedge[j + 1].x, s2 = nedge[j + 2].x, s3 = nedge[j + 3].x;
            bf16x8 v0 = *(const bf16x8*)(xin + (size_t)s0 * F + col8);
            bf16x8 v1 = *(const bf16x8*)(xin + (size_t)s1 * F + col8);
            bf16x8 v2 = *(const bf16x8*)(xin + (size_t)s2 * F + col8);
            bf16x8 v3 = *(const bf16x8*)(xin + (size_t)s3 * F + col8);
            for (int i = 0; i < 8; i++)
                a[i] += (b2f((unsigned short)v0[i]) + b2f((unsigned short)v1[i]))
                      + (b2f((unsigned short)v2[i]) + b2f((unsigned short)v3[i]));
        }
        for (; j < end; j++) {
            int s0 = nedge[j].x;
            bf16x8 v0 = *(const bf16x8*)(xin + (size_t)s0 * F + col8);
            for (int i = 0; i < 8; i++) a[i] += b2f((unsigned short)v0[i]);
        }
        float inv = 1.0f / fmaxf((float)(end - beg), 1.0f);
        unsigned short o[8];
        for (int i = 0; i < 8; i++) o[i] = f2b((a[i] + b[i]) * inv);
        *(bf16x8*)&lds[wave][batch * 4 + g][col8] = *(bf16x8*)o;
    }
    __syncthreads();   // REQUIRED: cross-lane LDS visibility

    // ---- Phase B ----
    int c = lane & 15, q = lane >> 4;
    f32x4 acc[8];
    for (int nt = 0; nt < 8; nt++) {
        float b = bias[nt * 16 + c];
        acc[nt] = (f32x4){b, b, b, b};
    }
    int mrow = m0 + c; if (mrow > NN - 1) mrow = NN - 1;
    for (int op = 0; op < 2; op++) {
        const unsigned short* W = op ? W2 : W1;
        for (int kb = 0; kb < 4; kb++) {
            bf16x8 a;
            if (op == 0) a = *(const bf16x8*)&lds[wave][c][kb * 32 + q * 8];
            else         a = *(const bf16x8*)(xin + (size_t)mrow * F + kb * 32 + q * 8);
            for (int nt = 0; nt < 8; nt++) {
                bf16x8 b = *(const bf16x8*)(W + (size_t)(nt * 16 + c) * F + kb * 32 + q * 8);
                acc[nt] = __builtin_amdgcn_mfma_f32_16x16x32_bf16(a, b, acc[nt], 0, 0, 0);
            }
        }
    }
#pragma unroll
    for (int r = 0; r < 4; r++) {
        int node = m0 + q * 4 + r;
        if (node < NN) {
            unsigned short o[8];
#pragma unroll
            for (int nt = 0; nt < 8; nt++) o[nt] = f2b(fmaxf(acc[nt][r], 0.0f));
            *(bf16x8*)(out + (size_t)node * F + c * 8) = *(bf16x8*)o;
        }
    }
}

// ---------------- PQ GEMM (wave-split N, permuted out cols): PQ[n] bf16 [N,512] ----------
__global__ __launch_bounds__(256) void pq_gemm_kernel(
    const unsigned short* __restrict__ h,
    const unsigned short* __restrict__ wmb,
    const float* __restrict__ bm1,
    unsigned short* __restrict__ PQ) {
    int wave = threadIdx.x >> 6, lane = threadIdx.x & 63;
    int c = lane & 15, q = lane >> 4;
    int half = wave >> 1, ntBase = (wave & 1) * 8;
    int m0 = blockIdx.x * 16;
    int mrow = m0 + c; if (mrow > NN - 1) mrow = NN - 1;
    bf16x8 a[4];
#pragma unroll
    for (int kb = 0; kb < 4; kb++)
        a[kb] = *(const bf16x8*)(h + (size_t)mrow * F + kb * 32 + q * 8);
    f32x4 acc[8];
#pragma unroll
    for (int nt = 0; nt < 8; nt++) {
        float b = half ? bm1[(ntBase + nt) * 16 + c] : 0.0f;
        acc[nt] = (f32x4){b, b, b, b};
    }
#pragma unroll
    for (int kb = 0; kb < 4; kb++) {
#pragma unroll
        for (int nt = 0; nt < 8; nt++) {
            bf16x8 b = *(const bf16x8*)(wmb + (size_t)((ntBase + nt) * 16 + c) * 256 + half * 128 + kb * 32 + q * 8);
            acc[nt] = __builtin_amdgcn_mfma_f32_16x16x32_bf16(a[kb], b, acc[nt], 0, 0, 0);
        }
    }
#pragma unroll
    for (int r = 0; r < 4; r++) {
        int node = m0 + q * 4 + r;
        if (node < NN) {
            unsigned short o[8];
#pragma unroll
            for (int nt = 0; nt < 8; nt++) o[nt] = f2b(acc[nt][r]);
            *(bf16x8*)(PQ + (size_t)node * 512 + half * 256 + c * 16 + ntBase) = *(bf16x8*)o;
        }
    }
}

// ---------------- edge dot: out[eid] = relu(P[src]+Q[dst]).Wm2p + bm2 ----------------
// One wave per dst node; 16 lanes/edge, x2 unroll (8 edges in flight/wave); packed
// (src,eid) int2 loads; bf16 unpack via dword shift/mask.
__global__ __launch_bounds__(256) void edge_dot_kernel(
    const unsigned short* __restrict__ PQ,
    const int2* __restrict__ nedge, const int* __restrict__ rowstart,
    const float* __restrict__ Wm2, const float* __restrict__ bm2,
    float* __restrict__ out) {
    int wave = threadIdx.x >> 6, lane = threadIdx.x & 63;
    int node = blockIdx.x * 4 + wave;
    if (node >= NN) return;
    int g = lane >> 4, l16 = lane & 15;
    int col = l16 * 16;
    float w2f[16], qf[16];
#pragma unroll
    for (int i = 0; i < 16; i++) w2f[i] = Wm2[i * 16 + l16];   // inverse perm gather
    {
        bf16x8 q0 = *(const bf16x8*)(PQ + (size_t)node * 512 + 256 + col);
        bf16x8 q1 = *(const bf16x8*)(PQ + (size_t)node * 512 + 256 + col + 8);
#pragma unroll
        for (int i = 0; i < 8; i++) { qf[i] = b2f((unsigned short)q0[i]); qf[8 + i] = b2f((unsigned short)q1[i]); }
    }
    float b2 = bm2[0];
    int beg = rowstart[node], end = rowstart[node + 1];
    int j = beg + g;
    for (; j + 4 < end; j += 8) {
        int2 e0 = nedge[j], e1 = nedge[j + 4];
        uint4 a0 = *(const uint4*)(PQ + (size_t)e0.x * 512 + col);
        uint4 a1 = *(const uint4*)(PQ + (size_t)e0.x * 512 + col + 8);
        uint4 c0 = *(const uint4*)(PQ + (size_t)e1.x * 512 + col);
        uint4 c1 = *(const uint4*)(PQ + (size_t)e1.x * 512 + col + 8);
        float t0 = 0.f, t1 = 0.f;
        unsigned int w0[8] = {a0.x, a0.y, a0.z, a0.w, a1.x, a1.y, a1.z, a1.w};
        unsigned int w1[8] = {c0.x, c0.y, c0.z, c0.w, c1.x, c1.y, c1.z, c1.w};
#pragma unroll
        for (int i = 0; i < 8; i++) {
            float lo0 = __uint_as_float(w0[i] << 16);
            float hi0 = __uint_as_float(w0[i] & 0xffff0000u);
            float lo1 = __uint_as_float(w1[i] << 16);
            float hi1 = __uint_as_float(w1[i] & 0xffff0000u);
            t0 += fmaxf(lo0 + qf[2 * i], 0.f) * w2f[2 * i]
                + fmaxf(hi0 + qf[2 * i + 1], 0.f) * w2f[2 * i + 1];
            t1 += fmaxf(lo1 + qf[2 * i], 0.f) * w2f[2 * i]
                + fmaxf(hi1 + qf[2 * i + 1], 0.f) * w2f[2 * i + 1];
        }
        t0 += __shfl_xor(t0, 1);  t1 += __shfl_xor(t1, 1);
        t0 += __shfl_xor(t0, 2);  t1 += __shfl_xor(t1, 2);
        t0 += __shfl_xor(t0, 4);  t1 += __shfl_xor(t1, 4);
        t0 += __shfl_xor(t0, 8);  t1 += __shfl_xor(t1, 8);
        if (l16 == 0) { out[e0.y] = t0 + b2; out[e1.y] = t1 + b2; }
    }
    for (; j < end; j += 4) {
        int2 e0 = nedge[j];
        uint4 a0 = *(const uint4*)(PQ + (size_t)e0.x * 512 + col);
        uint4 a1 = *(const uint4*)(PQ + (size_t)e0.x * 512 + col + 8);
        unsigned int w0[8] = {a0.x, a0.y, a0.z, a0.w, a1.x, a1.y, a1.z, a1.w};
        float t = 0.f;
#pragma unroll
        for (int i = 0; i < 8; i++) {
            float lo = __uint_as_float(w0[i] << 16);
            float hi = __uint_as_float(w0[i] & 0xffff0000u);
            t += fmaxf(lo + qf[2 * i], 0.f) * w2f[2 * i]
               + fmaxf(hi + qf[2 * i + 1], 0.f) * w2f[2 * i + 1];
        }
        t += __shfl_xor(t, 1);
        t += __shfl_xor(t, 2);
        t += __shfl_xor(t, 4);
        t += __shfl_xor(t, 8);
        if (l16 == 0) out[e0.y] = t + b2;
    }
}

extern "C" void kernel_launch(void* const* d_in, const int* in_sizes, int n_in,
                              void* d_out, int out_size, void* d_ws, size_t ws_size,
                              hipStream_t stream) {
    const float* x   = (const float*)d_in[0];
    const int*   ei  = (const int*)d_in[1];
    const float* W1l = (const float*)d_in[2];
    const float* b1l = (const float*)d_in[3];
    const float* W1r = (const float*)d_in[4];
    const float* W2l = (const float*)d_in[5];
    const float* b2l = (const float*)d_in[6];
    const float* W2r = (const float*)d_in[7];
    const float* Wm1 = (const float*)d_in[8];
    const float* bm1 = (const float*)d_in[9];
    const float* Wm2 = (const float*)d_in[10];
    const float* bm2 = (const float*)d_in[11];

    char* ws = (char*)d_ws;
    unsigned short* PQ       = (unsigned short*)(ws);
    unsigned short* xb       = (unsigned short*)(ws);
    unsigned short* h1       = (unsigned short*)(ws + 12800000);
    unsigned short* wb       = (unsigned short*)(ws + 51200000);
    int*            s32      = (int*)(ws + 51462144);
    int*            d32      = (int*)(ws + 54662144);
    int*            deg      = (int*)(ws + 57862144);
    int*            rowstart = (int*)(ws + 58062208);
    int*            cursor   = (int*)(ws + 58262272);
    int2*           nedge    = (int2*)(ws + 58462336);   // 800k x 8B = 6.4MB
    unsigned short* h2       = (unsigned short*)(ws + 64862336);
    int*            exloc    = (int*)(ws + 77662336);
    int*            bsum     = (int*)(ws + 77867136);
    float*          outp     = (float*)d_out;

    const unsigned short* w1l_b  = wb;
    const unsigned short* w1r_b  = wb + 16384;
    const unsigned short* w2l_p  = wb + 32768;
    const unsigned short* w2r_p  = wb + 49152;
    const unsigned short* wm1_p  = wb + 65536;

    // prep: combined cast+zero | cvt+hist | scan x2 | packed CSR fill
    cast_zero_kernel<<<6427, 256, 0, stream>>>(x, W1l, W1r, W2l, W2r, Wm1, xb, wb, deg);
    edge_cvt_hist_kernel<<<3125, 256, 0, stream>>>(ei, s32, d32, deg);
    scan_p1_kernel<<<50, 1024, 0, stream>>>(deg, exloc, bsum);
    scan_p3_kernel<<<50, 1024, 0, stream>>>(exloc, bsum, rowstart, cursor);
    fill_kernel<<<3125, 256, 0, stream>>>(s32, d32, cursor, nedge);

    // layer 1 (fused agg+combine; x unpermuted in, h1 pi-space out)
    sage_layer_kernel<<<782, 256, 0, stream>>>(xb, nedge, rowstart, w1l_b, w1r_b, b1l, h1);
    // layer 2 (h1 pi-space in with k-permuted W2, h2 pi-space out)
    sage_layer_kernel<<<782, 256, 0, stream>>>(h1, nedge, rowstart, w2l_p, w2r_p, b2l, h2);
    // edge MLP (decomposed; Wm1 k-permuted to match h2 pi-space)
    pq_gemm_kernel<<<3125, 256, 0, stream>>>(h2, wm1_p, bm1, PQ);
    edge_dot_kernel<<<12500, 256, 0, stream>>>(PQ, nedge, rowstart, Wm2, bm2, outp);
}